// Round 1
// baseline (3639.528 us; speedup 1.0000x reference)
//
#include <hip/hip_runtime.h>
#include <hip/hip_bf16.h>

#define N_NODES  100000
#define N_EDGES  1600000
#define D_NODE   128
#define D_EDGE   128
#define D_GLOB   16
#define D_HID    256
#define N_GRAPHS 64

using short8 = __attribute__((ext_vector_type(8))) short;
using f32x4  = __attribute__((ext_vector_type(4))) float;

__device__ __forceinline__ unsigned short f2b(float x) {
    __hip_bfloat16 h = __float2bfloat16(x);
    return *reinterpret_cast<unsigned short*>(&h);
}

// ---------------------------------------------------------------------------
// Prep: W1 (first 256 rows) -> bf16 transposed [n][k]; W2 -> bf16 [n][k];
// g[b][n] = b1[n] + sum_j u[b][j] * W1[256+j][n]   (64x256, tiny)
// ---------------------------------------------------------------------------
__global__ __launch_bounds__(256) void prep_kernel(
    const float* __restrict__ W1, const float* __restrict__ b1,
    const float* __restrict__ W2, const float* __restrict__ u,
    unsigned short* __restrict__ W1bT, unsigned short* __restrict__ W2bT,
    float* __restrict__ g)
{
    int tid = blockIdx.x * 256 + threadIdx.x;
    if (tid < 256 * 256) {
        int n = tid >> 8, k = tid & 255;                 // W1bT[n][k] = W1[k][n]
        W1bT[tid] = f2b(W1[k * 256 + n]);
    } else if (tid < 256 * 256 + 128 * 256) {
        int t = tid - 256 * 256;
        int n = t >> 8, k = t & 255;                     // W2bT[n][k] = W2[k][n]
        W2bT[t] = f2b(W2[k * 128 + n]);
    } else {
        int t = tid - (256 * 256 + 128 * 256);           // t < 64*256
        int b = t >> 8, n = t & 255;
        float s = b1[n];
        #pragma unroll
        for (int j = 0; j < 16; ++j)
            s += u[b * 16 + j] * W1[(256 + j) * 256 + n];
        g[t] = s;
    }
}

// ---------------------------------------------------------------------------
// Scatter-add edge_attr rows into agg[col].  thread = (edge, float4-chunk).
// ---------------------------------------------------------------------------
__global__ __launch_bounds__(256) void scatter_kernel(
    const int* __restrict__ ei, const float* __restrict__ ea,
    float* __restrict__ agg)
{
    int tid = blockIdx.x * 256 + threadIdx.x;
    int e = tid >> 5;        // 32 chunks of 4 floats per edge
    int c = tid & 31;
    int col = ei[N_EDGES + e];            // second row of edge_index
    float4 v = *reinterpret_cast<const float4*>(ea + (size_t)e * D_EDGE + c * 4);
    float* dst = agg + (size_t)col * D_EDGE + c * 4;
    unsafeAtomicAdd(dst + 0, v.x);
    unsafeAtomicAdd(dst + 1, v.y);
    unsafeAtomicAdd(dst + 2, v.z);
    unsafeAtomicAdd(dst + 3, v.w);
}

// ---------------------------------------------------------------------------
// Fused MLP: per block, 64 nodes.
//   hpre = [x|agg](bf16) @ W1bT^T  + g[batch]  -> relu -> H (bf16, LDS reuse)
//   out  = H @ W2bT^T + b2 + x
// MFMA 16x16x32 bf16. A/B frag: [idx=lane&15][k=quad*8+j]; C/D: col=lane&15,
// row=quad*4+reg (m89/m91-verified layouts).
// ---------------------------------------------------------------------------
__global__ __launch_bounds__(256) void mlp_kernel(
    const float* __restrict__ x, const float* __restrict__ agg,
    const int* __restrict__ batch,
    const unsigned short* __restrict__ W1bT, const unsigned short* __restrict__ W2bT,
    const float* __restrict__ g, const float* __restrict__ b2,
    float* __restrict__ out)
{
    __shared__ unsigned short Abuf[64][264];   // +8 bf16 pad: conflict-free b128 reads
    __shared__ int sbatch[64];

    const int tid  = threadIdx.x;
    const int wave = tid >> 6;
    const int lane = tid & 63;
    const int lm   = lane & 15;
    const int quad = lane >> 4;
    const int node0 = blockIdx.x * 64;

    // Stage A = [x | agg] as bf16 into LDS (zeros for tail rows)
    for (int i = tid; i < 64 * 64; i += 256) {
        int r = i >> 6, grp = i & 63;          // grp: 64 float4-groups per row
        int node = node0 + r;
        float4 v = make_float4(0.f, 0.f, 0.f, 0.f);
        if (node < N_NODES) {
            const float* src = (grp < 32)
                ? (x   + (size_t)node * D_NODE + grp * 4)
                : (agg + (size_t)node * D_EDGE + (grp - 32) * 4);
            v = *reinterpret_cast<const float4*>(src);
        }
        unsigned short* dst = &Abuf[r][grp * 4];
        dst[0] = f2b(v.x); dst[1] = f2b(v.y); dst[2] = f2b(v.z); dst[3] = f2b(v.w);
    }
    if (tid < 64) {
        int node = node0 + tid;
        sbatch[tid] = (node < N_NODES) ? batch[node] : 0;
    }
    __syncthreads();

    // ---- GEMM1: C1[64,256] = A[64,256] @ W1 ; wave handles 64 cols ----
    f32x4 acc[4][4];
    #pragma unroll
    for (int mi = 0; mi < 4; ++mi)
        #pragma unroll
        for (int ni = 0; ni < 4; ++ni)
            acc[mi][ni] = f32x4{0.f, 0.f, 0.f, 0.f};

    #pragma unroll
    for (int kt = 0; kt < 8; ++kt) {
        const int k0 = kt * 32 + quad * 8;
        short8 afrag[4], bfrag[4];
        #pragma unroll
        for (int mi = 0; mi < 4; ++mi)
            afrag[mi] = *reinterpret_cast<const short8*>(&Abuf[mi * 16 + lm][k0]);
        #pragma unroll
        for (int ni = 0; ni < 4; ++ni) {
            int n = wave * 64 + ni * 16 + lm;
            bfrag[ni] = *reinterpret_cast<const short8*>(&W1bT[n * 256 + k0]);
        }
        #pragma unroll
        for (int mi = 0; mi < 4; ++mi)
            #pragma unroll
            for (int ni = 0; ni < 4; ++ni)
                acc[mi][ni] = __builtin_amdgcn_mfma_f32_16x16x32_bf16(
                    afrag[mi], bfrag[ni], acc[mi][ni], 0, 0, 0);
    }
    __syncthreads();   // all waves done reading A before H overwrites it

    // Epilogue1: + g[batch], relu, write H (bf16) into the same LDS buffer
    #pragma unroll
    for (int mi = 0; mi < 4; ++mi) {
        #pragma unroll
        for (int ni = 0; ni < 4; ++ni) {
            int col = wave * 64 + ni * 16 + lm;
            #pragma unroll
            for (int r = 0; r < 4; ++r) {
                int row = mi * 16 + quad * 4 + r;
                float vv = acc[mi][ni][r] + g[sbatch[row] * 256 + col];
                vv = fmaxf(vv, 0.f);
                Abuf[row][col] = f2b(vv);
            }
        }
    }
    __syncthreads();

    // ---- GEMM2: C2[64,128] = H[64,256] @ W2 ; wave handles 32 cols ----
    f32x4 acc2[4][2];
    #pragma unroll
    for (int mi = 0; mi < 4; ++mi)
        #pragma unroll
        for (int ni = 0; ni < 2; ++ni)
            acc2[mi][ni] = f32x4{0.f, 0.f, 0.f, 0.f};

    #pragma unroll
    for (int kt = 0; kt < 8; ++kt) {
        const int k0 = kt * 32 + quad * 8;
        short8 afrag[4], bfrag[2];
        #pragma unroll
        for (int mi = 0; mi < 4; ++mi)
            afrag[mi] = *reinterpret_cast<const short8*>(&Abuf[mi * 16 + lm][k0]);
        #pragma unroll
        for (int ni = 0; ni < 2; ++ni) {
            int n = wave * 32 + ni * 16 + lm;
            bfrag[ni] = *reinterpret_cast<const short8*>(&W2bT[n * 256 + k0]);
        }
        #pragma unroll
        for (int mi = 0; mi < 4; ++mi)
            #pragma unroll
            for (int ni = 0; ni < 2; ++ni)
                acc2[mi][ni] = __builtin_amdgcn_mfma_f32_16x16x32_bf16(
                    afrag[mi], bfrag[ni], acc2[mi][ni], 0, 0, 0);
    }

    // Epilogue2: + b2 + residual x, store f32
    #pragma unroll
    for (int mi = 0; mi < 4; ++mi) {
        #pragma unroll
        for (int ni = 0; ni < 2; ++ni) {
            int col = wave * 32 + ni * 16 + lm;
            #pragma unroll
            for (int r = 0; r < 4; ++r) {
                int row = mi * 16 + quad * 4 + r;
                int node = node0 + row;
                if (node < N_NODES) {
                    out[(size_t)node * D_NODE + col] =
                        acc2[mi][ni][r] + b2[col] + x[(size_t)node * D_NODE + col];
                }
            }
        }
    }
}

// ---------------------------------------------------------------------------
extern "C" void kernel_launch(void* const* d_in, const int* in_sizes, int n_in,
                              void* d_out, int out_size, void* d_ws, size_t ws_size,
                              hipStream_t stream) {
    const float* x     = (const float*)d_in[0];
    const int*   ei    = (const int*)d_in[1];    // [2, N_EDGES]
    const float* ea    = (const float*)d_in[2];
    const float* u     = (const float*)d_in[3];
    const int*   batch = (const int*)d_in[4];
    const float* W1    = (const float*)d_in[5];  // [272, 256]
    const float* b1    = (const float*)d_in[6];
    const float* W2    = (const float*)d_in[7];  // [256, 128]
    const float* b2    = (const float*)d_in[8];
    float* out = (float*)d_out;

    char* ws = (char*)d_ws;
    float* agg = (float*)ws;
    size_t off = (size_t)N_NODES * D_EDGE * sizeof(float);      // 51.2 MB
    unsigned short* W1bT = (unsigned short*)(ws + off); off += 256 * 256 * 2;
    unsigned short* W2bT = (unsigned short*)(ws + off); off += 128 * 256 * 2;
    float* g = (float*)(ws + off);                              // 64*256 f32

    hipMemsetAsync(agg, 0, (size_t)N_NODES * D_EDGE * sizeof(float), stream);
    prep_kernel<<<(256 * 256 + 128 * 256 + 64 * 256) / 256, 256, 0, stream>>>(
        W1, b1, W2, u, W1bT, W2bT, g);
    scatter_kernel<<<(size_t)N_EDGES * 32 / 256, 256, 0, stream>>>(ei, ea, agg);
    mlp_kernel<<<(N_NODES + 63) / 64, 256, 0, stream>>>(
        x, agg, batch, W1bT, W2bT, g, b2, out);
}

// Round 2
// 1646.002 us; speedup vs baseline: 2.2111x; 2.2111x over previous
//
#include <hip/hip_runtime.h>
#include <hip/hip_bf16.h>

#define N_NODES  100000
#define N_EDGES  1600000
#define D_NODE   128
#define D_EDGE   128
#define D_GLOB   16
#define D_HID    256
#define N_GRAPHS 64

using short8 = __attribute__((ext_vector_type(8))) short;
using f32x4  = __attribute__((ext_vector_type(4))) float;

__device__ __forceinline__ unsigned short f2b(float x) {
    __hip_bfloat16 h = __float2bfloat16(x);
    return *reinterpret_cast<unsigned short*>(&h);
}

// ---------------------------------------------------------------------------
// Prep: W1 (first 256 rows) -> bf16 transposed [n][k]; W2 -> bf16 [n][k];
// g[b][n] = b1[n] + sum_j u[b][j] * W1[256+j][n]   (64x256, tiny)
// ---------------------------------------------------------------------------
__global__ __launch_bounds__(256) void prep_kernel(
    const float* __restrict__ W1, const float* __restrict__ b1,
    const float* __restrict__ W2, const float* __restrict__ u,
    unsigned short* __restrict__ W1bT, unsigned short* __restrict__ W2bT,
    float* __restrict__ g)
{
    int tid = blockIdx.x * 256 + threadIdx.x;
    if (tid < 256 * 256) {
        int n = tid >> 8, k = tid & 255;                 // W1bT[n][k] = W1[k][n]
        W1bT[tid] = f2b(W1[k * 256 + n]);
    } else if (tid < 256 * 256 + 128 * 256) {
        int t = tid - 256 * 256;
        int n = t >> 8, k = t & 255;                     // W2bT[n][k] = W2[k][n]
        W2bT[t] = f2b(W2[k * 128 + n]);
    } else {
        int t = tid - (256 * 256 + 128 * 256);           // t < 64*256
        int b = t >> 8, n = t & 255;
        float s = b1[n];
        #pragma unroll
        for (int j = 0; j < 16; ++j)
            s += u[b * 16 + j] * W1[(256 + j) * 256 + n];
        g[t] = s;
    }
}

// ---------------------------------------------------------------------------
// CSR build: degree histogram (int atomics only)
// ---------------------------------------------------------------------------
__global__ __launch_bounds__(256) void degree_kernel(
    const int* __restrict__ ei, int* __restrict__ deg)
{
    int e = blockIdx.x * 256 + threadIdx.x;   // grid covers N_EDGES exactly
    atomicAdd(&deg[ei[N_EDGES + e]], 1);
}

// Single-block exclusive scan of deg[100000] -> off[] and cursor[] copies.
__global__ __launch_bounds__(1024) void scan_kernel(
    const int* __restrict__ deg, int* __restrict__ off, int* __restrict__ cursor)
{
    __shared__ int part[1024];
    const int t = threadIdx.x;
    const int CHUNK = 98;                     // 1024*98 >= 100000
    int base = t * CHUNK;
    int s = 0;
    for (int i = 0; i < CHUNK; ++i) {
        int idx = base + i;
        if (idx < N_NODES) s += deg[idx];
    }
    part[t] = s;
    __syncthreads();
    for (int d = 1; d < 1024; d <<= 1) {      // Hillis-Steele inclusive scan
        int v = (t >= d) ? part[t - d] : 0;
        __syncthreads();
        part[t] += v;
        __syncthreads();
    }
    int run = (t == 0) ? 0 : part[t - 1];
    for (int i = 0; i < CHUNK; ++i) {
        int idx = base + i;
        if (idx < N_NODES) {
            off[idx] = run;
            cursor[idx] = run;
            run += deg[idx];
        }
    }
    if (t == 1023) off[N_NODES] = part[1023];
}

// Append edge ids into per-node buckets.
__global__ __launch_bounds__(256) void fill_kernel(
    const int* __restrict__ ei, int* __restrict__ cursor, int* __restrict__ bucket)
{
    int e = blockIdx.x * 256 + threadIdx.x;
    int col = ei[N_EDGES + e];
    int pos = atomicAdd(&cursor[col], 1);
    bucket[pos] = e;
}

// ---------------------------------------------------------------------------
// Gather: one wave per node; half-wave per edge row (32 lanes x float4 = 512B).
// Unroll x2 -> 4 row-loads in flight per wave. Writes every agg row (incl.
// degree-0 nodes), so no agg memset needed.
// ---------------------------------------------------------------------------
__global__ __launch_bounds__(256) void gather_kernel(
    const int* __restrict__ off, const int* __restrict__ bucket,
    const float* __restrict__ ea, float* __restrict__ agg)
{
    int w = (blockIdx.x * 256 + threadIdx.x) >> 6;   // wave id == node id
    if (w >= N_NODES) return;
    int lane = threadIdx.x & 63;
    int half = lane >> 5, l32 = lane & 31;
    int s  = off[w];
    int e1 = off[w + 1];
    float4 acc = make_float4(0.f, 0.f, 0.f, 0.f);

    int i = s + half;
    for (; i + 2 < e1; i += 4) {                     // 2 edges per half-wave iter
        int ea0 = bucket[i];
        int ea1 = bucket[i + 2];
        float4 v0 = *reinterpret_cast<const float4*>(ea + (size_t)ea0 * D_EDGE + l32 * 4);
        float4 v1 = *reinterpret_cast<const float4*>(ea + (size_t)ea1 * D_EDGE + l32 * 4);
        acc.x += v0.x + v1.x; acc.y += v0.y + v1.y;
        acc.z += v0.z + v1.z; acc.w += v0.w + v1.w;
    }
    for (; i < e1; i += 2) {
        int e = bucket[i];
        float4 v = *reinterpret_cast<const float4*>(ea + (size_t)e * D_EDGE + l32 * 4);
        acc.x += v.x; acc.y += v.y; acc.z += v.z; acc.w += v.w;
    }
    acc.x += __shfl_xor(acc.x, 32);
    acc.y += __shfl_xor(acc.y, 32);
    acc.z += __shfl_xor(acc.z, 32);
    acc.w += __shfl_xor(acc.w, 32);
    if (half == 0)
        *reinterpret_cast<float4*>(agg + (size_t)w * D_EDGE + l32 * 4) = acc;
}

// ---------------------------------------------------------------------------
// Fused MLP (unchanged from R0): per block, 64 nodes; MFMA 16x16x32 bf16.
// A/B frag: [idx=lane&15][k=quad*8+j]; C/D: col=lane&15, row=quad*4+reg.
// ---------------------------------------------------------------------------
__global__ __launch_bounds__(256) void mlp_kernel(
    const float* __restrict__ x, const float* __restrict__ agg,
    const int* __restrict__ batch,
    const unsigned short* __restrict__ W1bT, const unsigned short* __restrict__ W2bT,
    const float* __restrict__ g, const float* __restrict__ b2,
    float* __restrict__ out)
{
    __shared__ unsigned short Abuf[64][264];   // +8 bf16 pad: conflict-free b128
    __shared__ int sbatch[64];

    const int tid  = threadIdx.x;
    const int wave = tid >> 6;
    const int lane = tid & 63;
    const int lm   = lane & 15;
    const int quad = lane >> 4;
    const int node0 = blockIdx.x * 64;

    for (int i = tid; i < 64 * 64; i += 256) {
        int r = i >> 6, grp = i & 63;
        int node = node0 + r;
        float4 v = make_float4(0.f, 0.f, 0.f, 0.f);
        if (node < N_NODES) {
            const float* src = (grp < 32)
                ? (x   + (size_t)node * D_NODE + grp * 4)
                : (agg + (size_t)node * D_EDGE + (grp - 32) * 4);
            v = *reinterpret_cast<const float4*>(src);
        }
        unsigned short* dst = &Abuf[r][grp * 4];
        dst[0] = f2b(v.x); dst[1] = f2b(v.y); dst[2] = f2b(v.z); dst[3] = f2b(v.w);
    }
    if (tid < 64) {
        int node = node0 + tid;
        sbatch[tid] = (node < N_NODES) ? batch[node] : 0;
    }
    __syncthreads();

    // ---- GEMM1: C1[64,256] = A[64,256] @ W1 ----
    f32x4 acc[4][4];
    #pragma unroll
    for (int mi = 0; mi < 4; ++mi)
        #pragma unroll
        for (int ni = 0; ni < 4; ++ni)
            acc[mi][ni] = f32x4{0.f, 0.f, 0.f, 0.f};

    #pragma unroll
    for (int kt = 0; kt < 8; ++kt) {
        const int k0 = kt * 32 + quad * 8;
        short8 afrag[4], bfrag[4];
        #pragma unroll
        for (int mi = 0; mi < 4; ++mi)
            afrag[mi] = *reinterpret_cast<const short8*>(&Abuf[mi * 16 + lm][k0]);
        #pragma unroll
        for (int ni = 0; ni < 4; ++ni) {
            int n = wave * 64 + ni * 16 + lm;
            bfrag[ni] = *reinterpret_cast<const short8*>(&W1bT[n * 256 + k0]);
        }
        #pragma unroll
        for (int mi = 0; mi < 4; ++mi)
            #pragma unroll
            for (int ni = 0; ni < 4; ++ni)
                acc[mi][ni] = __builtin_amdgcn_mfma_f32_16x16x32_bf16(
                    afrag[mi], bfrag[ni], acc[mi][ni], 0, 0, 0);
    }
    __syncthreads();

    #pragma unroll
    for (int mi = 0; mi < 4; ++mi) {
        #pragma unroll
        for (int ni = 0; ni < 4; ++ni) {
            int col = wave * 64 + ni * 16 + lm;
            #pragma unroll
            for (int r = 0; r < 4; ++r) {
                int row = mi * 16 + quad * 4 + r;
                float vv = acc[mi][ni][r] + g[sbatch[row] * 256 + col];
                vv = fmaxf(vv, 0.f);
                Abuf[row][col] = f2b(vv);
            }
        }
    }
    __syncthreads();

    // ---- GEMM2: C2[64,128] = H[64,256] @ W2 ----
    f32x4 acc2[4][2];
    #pragma unroll
    for (int mi = 0; mi < 4; ++mi)
        #pragma unroll
        for (int ni = 0; ni < 2; ++ni)
            acc2[mi][ni] = f32x4{0.f, 0.f, 0.f, 0.f};

    #pragma unroll
    for (int kt = 0; kt < 8; ++kt) {
        const int k0 = kt * 32 + quad * 8;
        short8 afrag[4], bfrag[2];
        #pragma unroll
        for (int mi = 0; mi < 4; ++mi)
            afrag[mi] = *reinterpret_cast<const short8*>(&Abuf[mi * 16 + lm][k0]);
        #pragma unroll
        for (int ni = 0; ni < 2; ++ni) {
            int n = wave * 32 + ni * 16 + lm;
            bfrag[ni] = *reinterpret_cast<const short8*>(&W2bT[n * 256 + k0]);
        }
        #pragma unroll
        for (int mi = 0; mi < 4; ++mi)
            #pragma unroll
            for (int ni = 0; ni < 2; ++ni)
                acc2[mi][ni] = __builtin_amdgcn_mfma_f32_16x16x32_bf16(
                    afrag[mi], bfrag[ni], acc2[mi][ni], 0, 0, 0);
    }

    #pragma unroll
    for (int mi = 0; mi < 4; ++mi) {
        #pragma unroll
        for (int ni = 0; ni < 2; ++ni) {
            int col = wave * 32 + ni * 16 + lm;
            #pragma unroll
            for (int r = 0; r < 4; ++r) {
                int row = mi * 16 + quad * 4 + r;
                int node = node0 + row;
                if (node < N_NODES) {
                    out[(size_t)node * D_NODE + col] =
                        acc2[mi][ni][r] + b2[col] + x[(size_t)node * D_NODE + col];
                }
            }
        }
    }
}

// ---------------------------------------------------------------------------
extern "C" void kernel_launch(void* const* d_in, const int* in_sizes, int n_in,
                              void* d_out, int out_size, void* d_ws, size_t ws_size,
                              hipStream_t stream) {
    const float* x     = (const float*)d_in[0];
    const int*   ei    = (const int*)d_in[1];    // [2, N_EDGES]
    const float* ea    = (const float*)d_in[2];
    const float* u     = (const float*)d_in[3];
    const int*   batch = (const int*)d_in[4];
    const float* W1    = (const float*)d_in[5];  // [272, 256]
    const float* b1    = (const float*)d_in[6];
    const float* W2    = (const float*)d_in[7];  // [256, 128]
    const float* b2    = (const float*)d_in[8];
    float* out = (float*)d_out;

    char* ws = (char*)d_ws;
    size_t off_b = 0;
    float* agg = (float*)(ws + off_b);  off_b += (size_t)N_NODES * D_EDGE * sizeof(float);
    unsigned short* W1bT = (unsigned short*)(ws + off_b); off_b += 256 * 256 * 2;
    unsigned short* W2bT = (unsigned short*)(ws + off_b); off_b += 128 * 256 * 2;
    float* g = (float*)(ws + off_b);    off_b += 64 * 256 * sizeof(float);
    int* deg    = (int*)(ws + off_b);   off_b += (N_NODES + 16) * sizeof(int);
    int* offs   = (int*)(ws + off_b);   off_b += (N_NODES + 16) * sizeof(int);
    int* cursor = (int*)(ws + off_b);   off_b += (N_NODES + 16) * sizeof(int);
    int* bucket = (int*)(ws + off_b);   off_b += (size_t)N_EDGES * sizeof(int);

    hipMemsetAsync(deg, 0, N_NODES * sizeof(int), stream);
    prep_kernel<<<(256 * 256 + 128 * 256 + 64 * 256) / 256, 256, 0, stream>>>(
        W1, b1, W2, u, W1bT, W2bT, g);
    degree_kernel<<<N_EDGES / 256, 256, 0, stream>>>(ei, deg);
    scan_kernel<<<1, 1024, 0, stream>>>(deg, offs, cursor);
    fill_kernel<<<N_EDGES / 256, 256, 0, stream>>>(ei, cursor, bucket);
    gather_kernel<<<(N_NODES * 64 + 255) / 256, 256, 0, stream>>>(offs, bucket, ea, agg);
    mlp_kernel<<<(N_NODES + 63) / 64, 256, 0, stream>>>(
        x, agg, batch, W1bT, W2bT, g, b2, out);
}